// Round 1
// baseline (510.816 us; speedup 1.0000x reference)
//
#include <hip/hip_runtime.h>
#include <math.h>

// Problem constants (B,S,D,H) = (8, 2048, 1024, 4), HD = 256
#define BB 8
#define SS 2048
#define DD 1024
#define HH 4
#define HDD 256
#define ROWS 16              // rows per block in k1
#define NROW (BB*SS)         // 16384

// Workspace layout (float offsets)
#define OFF_MU_T 0
#define OFF_RS_T (NROW)
#define OFF_MU_I (2*NROW)
#define OFF_RS_I (3*NROW)
#define OFF_TG   (4*NROW)                 // text_global sum  [B*D]
#define OFF_IG   (4*NROW + BB*DD)         // image_global sum [B*D]
#define OFF_SIM  (4*NROW + 2*BB*DD)       // per_pos_sim sum  [B]
#define OFF_LOGIT (OFF_SIM + BB)          // fc logit         [B]
#define ZERO_CNT (2*BB*DD + 2*BB)         // floats to zero starting at OFF_TG

__device__ __forceinline__ float wred(float v) {
#pragma unroll
  for (int m = 32; m > 0; m >>= 1) v += __shfl_xor(v, m, 64);
  return v;
}

__global__ __launch_bounds__(256) void kz(float* p, int n) {
  int i = blockIdx.x * 256 + threadIdx.x;
  if (i < n) p[i] = 0.f;
}

// Pass 1: per-row layernorm stats, per-position cosine sim, global mean sums.
__global__ __launch_bounds__(256) void k1_stats(
    const float* __restrict__ text, const float* __restrict__ image,
    const float* __restrict__ wt, const float* __restrict__ bt,
    const float* __restrict__ wi, const float* __restrict__ bi,
    float* __restrict__ ws)
{
  const int tid  = threadIdx.x;
  const int lane = tid & 63;
  const int wv   = tid >> 6;
  const int b    = blockIdx.x >> 7;             // / (SS/ROWS) = /128
  const int s0   = (blockIdx.x & 127) * ROWS;
  const int d0   = tid << 2;

  __shared__ float red[16];
  __shared__ float bc[4];

  const float4 wt4 = *(const float4*)(wt + d0);
  const float4 bt4 = *(const float4*)(bt + d0);
  const float4 wi4 = *(const float4*)(wi + d0);
  const float4 bi4 = *(const float4*)(bi + d0);

  float tga[4] = {0,0,0,0}, iga[4] = {0,0,0,0};
  float sim_loc = 0.f;

  for (int r = 0; r < ROWS; ++r) {
    const int row = b*SS + s0 + r;
    const float4 t4 = *(const float4*)(text  + (size_t)row*DD + d0);
    const float4 i4 = *(const float4*)(image + (size_t)row*DD + d0);

    float v0 = t4.x + t4.y + t4.z + t4.w;
    float v1 = t4.x*t4.x + t4.y*t4.y + t4.z*t4.z + t4.w*t4.w;
    float v2 = i4.x + i4.y + i4.z + i4.w;
    float v3 = i4.x*i4.x + i4.y*i4.y + i4.z*i4.z + i4.w*i4.w;
    v0 = wred(v0); v1 = wred(v1); v2 = wred(v2); v3 = wred(v3);
    if (lane == 0) { red[wv*4+0]=v0; red[wv*4+1]=v1; red[wv*4+2]=v2; red[wv*4+3]=v3; }
    __syncthreads();
    if (tid == 0) {
      float st  = red[0]+red[4]+red[8]+red[12];
      float sst = red[1]+red[5]+red[9]+red[13];
      float si  = red[2]+red[6]+red[10]+red[14];
      float ssi = red[3]+red[7]+red[11]+red[15];
      const float invD = 1.f/DD;
      float mt = st*invD, vt = sst*invD - mt*mt;
      float mi = si*invD, vi = ssi*invD - mi*mi;
      float rt = rsqrtf(vt + 1e-5f);
      float ri = rsqrtf(vi + 1e-5f);
      bc[0]=mt; bc[1]=rt; bc[2]=mi; bc[3]=ri;
      ws[OFF_MU_T+row]=mt; ws[OFF_RS_T+row]=rt;
      ws[OFF_MU_I+row]=mi; ws[OFF_RS_I+row]=ri;
    }
    __syncthreads();
    const float mt=bc[0], rt=bc[1], mi=bc[2], ri=bc[3];
    float tn[4], inn[4];
    tn[0]  = (t4.x-mt)*rt*wt4.x + bt4.x;
    tn[1]  = (t4.y-mt)*rt*wt4.y + bt4.y;
    tn[2]  = (t4.z-mt)*rt*wt4.z + bt4.z;
    tn[3]  = (t4.w-mt)*rt*wt4.w + bt4.w;
    inn[0] = (i4.x-mi)*ri*wi4.x + bi4.x;
    inn[1] = (i4.y-mi)*ri*wi4.y + bi4.y;
    inn[2] = (i4.z-mi)*ri*wi4.z + bi4.z;
    inn[3] = (i4.w-mi)*ri*wi4.w + bi4.w;
    float dv=0.f, nt2=0.f, ni2=0.f;
#pragma unroll
    for (int j=0;j<4;++j) {
      tga[j]+=tn[j]; iga[j]+=inn[j];
      dv += tn[j]*inn[j]; nt2 += tn[j]*tn[j]; ni2 += inn[j]*inn[j];
    }
    dv = wred(dv); nt2 = wred(nt2); ni2 = wred(ni2);
    if (lane == 0) { red[wv*4+0]=dv; red[wv*4+1]=nt2; red[wv*4+2]=ni2; }
    __syncthreads();
    if (tid == 0) {
      float d_all = red[0]+red[4]+red[8]+red[12];
      float nt = fmaxf(sqrtf(red[1]+red[5]+red[9]+red[13]), 1e-6f);
      float ni = fmaxf(sqrtf(red[2]+red[6]+red[10]+red[14]), 1e-6f);
      sim_loc += d_all / (nt*ni);
    }
    __syncthreads();
  }
#pragma unroll
  for (int j=0;j<4;++j) {
    atomicAdd(&ws[OFF_TG + b*DD + d0 + j], tga[j]);
    atomicAdd(&ws[OFF_IG + b*DD + d0 + j], iga[j]);
  }
  if (tid == 0) atomicAdd(&ws[OFF_SIM + b], sim_loc);
}

// Gate network: gates = relu(Wa@tg + Wq@ig + biases + sim_feat); logit[b] = gates . fc_w
__global__ __launch_bounds__(256) void k2_gates(
    const float* __restrict__ Wa, const float* __restrict__ Wab,
    const float* __restrict__ Wq, const float* __restrict__ Wqb,
    const float* __restrict__ simw, const float* __restrict__ simb,
    const float* __restrict__ fcw, float* __restrict__ ws)
{
  const int h = blockIdx.x;
  const int b = blockIdx.y;
  const int tid  = threadIdx.x;
  const int lane = tid & 63;
  const int wv   = tid >> 6;
  __shared__ float tg_l[DD], ig_l[DD];
  {
    const int d0 = tid << 2;
    float4 t = *(const float4*)(ws + OFF_TG + b*DD + d0);
    float4 i = *(const float4*)(ws + OFF_IG + b*DD + d0);
    const float inv = 1.f/SS;
    *(float4*)(tg_l + d0) = make_float4(t.x*inv, t.y*inv, t.z*inv, t.w*inv);
    *(float4*)(ig_l + d0) = make_float4(i.x*inv, i.y*inv, i.z*inv, i.w*inv);
  }
  __syncthreads();
  const float gs = ws[OFF_SIM + b] * (1.f/SS);   // global_sim[b]
  float wl = 0.f;
  for (int kk = 0; kk < 64; ++kk) {
    const int k = wv*64 + kk;
    const float* wa_row = Wa + ((size_t)h*HDD + k)*DD;
    const float* wq_row = Wq + ((size_t)h*HDD + k)*DD;
    float acc = 0.f;
#pragma unroll
    for (int st = 0; st < 4; ++st) {
      const int d = st*256 + (lane<<2);
      const float4 a  = *(const float4*)(wa_row + d);
      const float4 q  = *(const float4*)(wq_row + d);
      const float4 tg = *(const float4*)(tg_l + d);
      const float4 ig = *(const float4*)(ig_l + d);
      acc += a.x*tg.x + a.y*tg.y + a.z*tg.z + a.w*tg.w;
      acc += q.x*ig.x + q.y*ig.y + q.z*ig.z + q.w*ig.w;
    }
    acc = wred(acc);
    if (lane == 0) {
      const int gk = h*HDD + k;
      float gate = acc + Wab[gk] + Wqb[gk] + gs*simw[k] + simb[k];
      gate = fmaxf(gate, 0.f);
      wl += gate * fcw[gk];
    }
  }
  if (lane == 0) atomicAdd(&ws[OFF_LOGIT + b], wl);
}

// Pass 2: recompute normalization from stored (mu, rstd), blend with g, write out.
__global__ __launch_bounds__(256) void k3_blend(
    const float* __restrict__ text, const float* __restrict__ image,
    const float* __restrict__ wt, const float* __restrict__ bt,
    const float* __restrict__ wi, const float* __restrict__ bi,
    const float* __restrict__ fcb,
    const float* __restrict__ ws, float* __restrict__ out)
{
  const int row = blockIdx.x;
  const int b   = row >> 11;    // / SS
  const int d0  = threadIdx.x << 2;
  const float g  = 1.f / (1.f + expf(-(ws[OFF_LOGIT+b] + fcb[0])));
  const float gi = 1.f - g;
  const float mt = ws[OFF_MU_T+row], rt = ws[OFF_RS_T+row];
  const float mi = ws[OFF_MU_I+row], ri = ws[OFF_RS_I+row];
  const float4 t4  = *(const float4*)(text  + (size_t)row*DD + d0);
  const float4 i4  = *(const float4*)(image + (size_t)row*DD + d0);
  const float4 wt4 = *(const float4*)(wt + d0);
  const float4 bt4 = *(const float4*)(bt + d0);
  const float4 wi4 = *(const float4*)(wi + d0);
  const float4 bi4 = *(const float4*)(bi + d0);
  float4 o;
  o.x = g*((t4.x-mt)*rt*wt4.x + bt4.x) + gi*((i4.x-mi)*ri*wi4.x + bi4.x);
  o.y = g*((t4.y-mt)*rt*wt4.y + bt4.y) + gi*((i4.y-mi)*ri*wi4.y + bi4.y);
  o.z = g*((t4.z-mt)*rt*wt4.z + bt4.z) + gi*((i4.z-mi)*ri*wi4.z + bi4.z);
  o.w = g*((t4.w-mt)*rt*wt4.w + bt4.w) + gi*((i4.w-mi)*ri*wi4.w + bi4.w);
  *(float4*)(out + (size_t)row*DD + d0) = o;
}

extern "C" void kernel_launch(void* const* d_in, const int* in_sizes, int n_in,
                              void* d_out, int out_size, void* d_ws, size_t ws_size,
                              hipStream_t stream)
{
  const float* text   = (const float*)d_in[0];
  const float* image  = (const float*)d_in[1];
  const float* ln_t_w = (const float*)d_in[2];
  const float* ln_t_b = (const float*)d_in[3];
  const float* ln_i_w = (const float*)d_in[4];
  const float* ln_i_b = (const float*)d_in[5];
  const float* Wa     = (const float*)d_in[6];
  const float* Wab    = (const float*)d_in[7];
  const float* Wq     = (const float*)d_in[8];
  const float* Wqb    = (const float*)d_in[9];
  const float* simw   = (const float*)d_in[10];
  const float* simb   = (const float*)d_in[11];
  const float* fcw    = (const float*)d_in[12];
  const float* fcb    = (const float*)d_in[13];
  float* ws  = (float*)d_ws;
  float* out = (float*)d_out;

  kz<<<(ZERO_CNT + 255) / 256, 256, 0, stream>>>(ws + OFF_TG, ZERO_CNT);
  k1_stats<<<NROW / ROWS, 256, 0, stream>>>(text, image, ln_t_w, ln_t_b, ln_i_w, ln_i_b, ws);
  k2_gates<<<dim3(HH, BB), 256, 0, stream>>>(Wa, Wab, Wq, Wqb, simw, simb, fcw, ws);
  k3_blend<<<NROW, 256, 0, stream>>>(text, image, ln_t_w, ln_t_b, ln_i_w, ln_i_b, fcb, ws, out);
}

// Round 2
// 292.294 us; speedup vs baseline: 1.7476x; 1.7476x over previous
//
#include <hip/hip_runtime.h>
#include <math.h>

// Problem constants (B,S,D,H) = (8, 2048, 1024, 4), HD = 256
#define BB 8
#define SS 2048
#define DD 1024
#define HH 4
#define HDD 256
#define NROW (BB*SS)         // 16384
#define RW 4                 // rows per wave in k1

// Workspace layout (float offsets)
#define OFF_MU_T 0
#define OFF_RS_T (NROW)
#define OFF_MU_I (2*NROW)
#define OFF_RS_I (3*NROW)
#define OFF_TG   (4*NROW)                 // text_global sum  [B*D]
#define OFF_IG   (4*NROW + BB*DD)         // image_global sum [B*D]
#define OFF_SIM  (4*NROW + 2*BB*DD)       // per_pos_sim sum  [B]
#define OFF_LOGIT (OFF_SIM + BB)          // fc logit         [B]
#define ZERO_CNT (2*BB*DD + 2*BB)         // floats to zero starting at OFF_TG

__device__ __forceinline__ float wred(float v) {
#pragma unroll
  for (int m = 32; m > 0; m >>= 1) v += __shfl_xor(v, m, 64);
  return v;
}

__global__ __launch_bounds__(256) void kz(float* p, int n) {
  int i = blockIdx.x * 256 + threadIdx.x;
  if (i < n) p[i] = 0.f;
}

// Pass 1: wave-per-row layernorm stats + cosine sim + global-mean partials.
// Each wave owns RW=4 full rows (16 floats/lane); all row reductions are
// barrier-free shfl_xor butterflies. One __syncthreads per block, at the end,
// for the block-level accumulation of the global-mean sums.
__global__ __launch_bounds__(256) void k1_stats(
    const float* __restrict__ text, const float* __restrict__ image,
    const float* __restrict__ wt, const float* __restrict__ bt,
    const float* __restrict__ wi, const float* __restrict__ bi,
    float* __restrict__ ws)
{
  const int tid  = threadIdx.x;
  const int lane = tid & 63;
  const int wv   = tid >> 6;
  const int wave_id = blockIdx.x * 4 + wv;     // 0..4095
  const int row0 = wave_id * RW;               // 4 consecutive rows per wave
  const int b    = row0 >> 11;                 // / SS; constant per block
  const int c0   = lane << 2;                  // lane's float4 base within a 256-col chunk

  // LN params held in registers (L1-hot loads, done once)
  float4 wt4[4], bt4[4], wi4[4], bi4[4];
#pragma unroll
  for (int c = 0; c < 4; ++c) {
    wt4[c] = *(const float4*)(wt + c*256 + c0);
    bt4[c] = *(const float4*)(bt + c*256 + c0);
    wi4[c] = *(const float4*)(wi + c*256 + c0);
    bi4[c] = *(const float4*)(bi + c*256 + c0);
  }

  float tga[16], iga[16];
#pragma unroll
  for (int j = 0; j < 16; ++j) { tga[j] = 0.f; iga[j] = 0.f; }
  float sim_loc = 0.f;

  for (int r = 0; r < RW; ++r) {
    const int row = row0 + r;
    const float* tp = text  + (size_t)row * DD;
    const float* ip = image + (size_t)row * DD;
    float4 t4[4], i4[4];
#pragma unroll
    for (int c = 0; c < 4; ++c) {
      t4[c] = *(const float4*)(tp + c*256 + c0);
      i4[c] = *(const float4*)(ip + c*256 + c0);
    }
    float st=0.f, sst=0.f, si=0.f, ssi=0.f;
#pragma unroll
    for (int c = 0; c < 4; ++c) {
      st  += t4[c].x + t4[c].y + t4[c].z + t4[c].w;
      sst += t4[c].x*t4[c].x + t4[c].y*t4[c].y + t4[c].z*t4[c].z + t4[c].w*t4[c].w;
      si  += i4[c].x + i4[c].y + i4[c].z + i4[c].w;
      ssi += i4[c].x*i4[c].x + i4[c].y*i4[c].y + i4[c].z*i4[c].z + i4[c].w*i4[c].w;
    }
    st = wred(st); sst = wred(sst); si = wred(si); ssi = wred(ssi);
    const float invD = 1.f/DD;
    const float mt = st*invD,  vt = sst*invD - mt*mt;
    const float mi = si*invD,  vi = ssi*invD - mi*mi;
    const float rt = rsqrtf(vt + 1e-5f);
    const float ri = rsqrtf(vi + 1e-5f);
    if (lane == 0) {
      ws[OFF_MU_T+row]=mt; ws[OFF_RS_T+row]=rt;
      ws[OFF_MU_I+row]=mi; ws[OFF_RS_I+row]=ri;
    }
    float dv=0.f, nt2=0.f, ni2=0.f;
#pragma unroll
    for (int c = 0; c < 4; ++c) {
      const float tv[4] = {t4[c].x, t4[c].y, t4[c].z, t4[c].w};
      const float iv[4] = {i4[c].x, i4[c].y, i4[c].z, i4[c].w};
      const float wtv[4] = {wt4[c].x, wt4[c].y, wt4[c].z, wt4[c].w};
      const float btv[4] = {bt4[c].x, bt4[c].y, bt4[c].z, bt4[c].w};
      const float wiv[4] = {wi4[c].x, wi4[c].y, wi4[c].z, wi4[c].w};
      const float biv[4] = {bi4[c].x, bi4[c].y, bi4[c].z, bi4[c].w};
#pragma unroll
      for (int j = 0; j < 4; ++j) {
        const float tn  = (tv[j]-mt)*rt*wtv[j] + btv[j];
        const float inn = (iv[j]-mi)*ri*wiv[j] + biv[j];
        tga[c*4+j] += tn;  iga[c*4+j] += inn;
        dv += tn*inn;  nt2 += tn*tn;  ni2 += inn*inn;
      }
    }
    dv = wred(dv); nt2 = wred(nt2); ni2 = wred(ni2);
    const float nt = fmaxf(sqrtf(nt2), 1e-6f);
    const float ni = fmaxf(sqrtf(ni2), 1e-6f);
    sim_loc += dv / (nt*ni);
  }

  // Block-level accumulation of global-mean partials (all 4 waves share b)
  __shared__ float accs[2][4][DD];   // 32 KB
  __shared__ float sim_s[4];
#pragma unroll
  for (int c = 0; c < 4; ++c) {
    *(float4*)&accs[0][wv][c*256 + c0] = make_float4(tga[c*4+0], tga[c*4+1], tga[c*4+2], tga[c*4+3]);
    *(float4*)&accs[1][wv][c*256 + c0] = make_float4(iga[c*4+0], iga[c*4+1], iga[c*4+2], iga[c*4+3]);
  }
  if (lane == 0) sim_s[wv] = sim_loc;
  __syncthreads();
  const int col0 = tid << 2;
#pragma unroll
  for (int j = 0; j < 4; ++j) {
    const float ts = accs[0][0][col0+j] + accs[0][1][col0+j] + accs[0][2][col0+j] + accs[0][3][col0+j];
    const float is = accs[1][0][col0+j] + accs[1][1][col0+j] + accs[1][2][col0+j] + accs[1][3][col0+j];
    atomicAdd(&ws[OFF_TG + b*DD + col0 + j], ts);
    atomicAdd(&ws[OFF_IG + b*DD + col0 + j], is);
  }
  if (tid == 0) atomicAdd(&ws[OFF_SIM + b], sim_s[0]+sim_s[1]+sim_s[2]+sim_s[3]);
}

// Gate network: 256 blocks, each owns 4 (h,k) rows; every thread dots its
// float4 of the weight row against all 8 batch global-vectors (L2-hot).
__global__ __launch_bounds__(256) void k2_gates(
    const float* __restrict__ Wa, const float* __restrict__ Wab,
    const float* __restrict__ Wq, const float* __restrict__ Wqb,
    const float* __restrict__ simw, const float* __restrict__ simb,
    const float* __restrict__ fcw, float* __restrict__ ws)
{
  const int tid  = threadIdx.x;
  const int lane = tid & 63;
  const int wv   = tid >> 6;
  const int r0   = blockIdx.x * 4;       // flat (h,k) row base, 0..1023
  const int d0   = tid << 2;

  __shared__ float red[4][4][BB];        // [row][wave][b]

  for (int rr = 0; rr < 4; ++rr) {
    const int r = r0 + rr;
    const float4 a4 = *(const float4*)(Wa + (size_t)r*DD + d0);
    const float4 q4 = *(const float4*)(Wq + (size_t)r*DD + d0);
    float acc[BB];
#pragma unroll
    for (int b = 0; b < BB; ++b) {
      const float4 t = *(const float4*)(ws + OFF_TG + b*DD + d0);
      const float4 i = *(const float4*)(ws + OFF_IG + b*DD + d0);
      acc[b] = a4.x*t.x + a4.y*t.y + a4.z*t.z + a4.w*t.w
             + q4.x*i.x + q4.y*i.y + q4.z*i.z + q4.w*i.w;
    }
#pragma unroll
    for (int b = 0; b < BB; ++b) {
      acc[b] = wred(acc[b]);
      if (lane == 0) red[rr][wv][b] = acc[b];
    }
  }
  __syncthreads();
  if (tid < BB) {
    const int b = tid;
    const float inv = 1.f/SS;
    const float gs = ws[OFF_SIM + b] * inv;   // global_sim[b]
    float part = 0.f;
#pragma unroll
    for (int rr = 0; rr < 4; ++rr) {
      const int r = r0 + rr;
      const int k = r & 255;
      const float v = (red[rr][0][b] + red[rr][1][b] + red[rr][2][b] + red[rr][3][b]) * inv;
      float gate = v + Wab[r] + Wqb[r] + gs*simw[k] + simb[k];
      gate = fmaxf(gate, 0.f);
      part += gate * fcw[r];
    }
    atomicAdd(&ws[OFF_LOGIT + b], part);
  }
}

// Pass 2: recompute normalization from stored (mu, rstd), blend with g, write out.
__global__ __launch_bounds__(256) void k3_blend(
    const float* __restrict__ text, const float* __restrict__ image,
    const float* __restrict__ wt, const float* __restrict__ bt,
    const float* __restrict__ wi, const float* __restrict__ bi,
    const float* __restrict__ fcb,
    const float* __restrict__ ws, float* __restrict__ out)
{
  const int row = blockIdx.x;
  const int b   = row >> 11;    // / SS
  const int d0  = threadIdx.x << 2;
  const float g  = 1.f / (1.f + expf(-(ws[OFF_LOGIT+b] + fcb[0])));
  const float gi = 1.f - g;
  const float mt = ws[OFF_MU_T+row], rt = ws[OFF_RS_T+row];
  const float mi = ws[OFF_MU_I+row], ri = ws[OFF_RS_I+row];
  const float4 t4  = *(const float4*)(text  + (size_t)row*DD + d0);
  const float4 i4  = *(const float4*)(image + (size_t)row*DD + d0);
  const float4 wt4 = *(const float4*)(wt + d0);
  const float4 bt4 = *(const float4*)(bt + d0);
  const float4 wi4 = *(const float4*)(wi + d0);
  const float4 bi4 = *(const float4*)(bi + d0);
  float4 o;
  o.x = g*((t4.x-mt)*rt*wt4.x + bt4.x) + gi*((i4.x-mi)*ri*wi4.x + bi4.x);
  o.y = g*((t4.y-mt)*rt*wt4.y + bt4.y) + gi*((i4.y-mi)*ri*wi4.y + bi4.y);
  o.z = g*((t4.z-mt)*rt*wt4.z + bt4.z) + gi*((i4.z-mi)*ri*wi4.z + bi4.z);
  o.w = g*((t4.w-mt)*rt*wt4.w + bt4.w) + gi*((i4.w-mi)*ri*wi4.w + bi4.w);
  *(float4*)(out + (size_t)row*DD + d0) = o;
}

extern "C" void kernel_launch(void* const* d_in, const int* in_sizes, int n_in,
                              void* d_out, int out_size, void* d_ws, size_t ws_size,
                              hipStream_t stream)
{
  const float* text   = (const float*)d_in[0];
  const float* image  = (const float*)d_in[1];
  const float* ln_t_w = (const float*)d_in[2];
  const float* ln_t_b = (const float*)d_in[3];
  const float* ln_i_w = (const float*)d_in[4];
  const float* ln_i_b = (const float*)d_in[5];
  const float* Wa     = (const float*)d_in[6];
  const float* Wab    = (const float*)d_in[7];
  const float* Wq     = (const float*)d_in[8];
  const float* Wqb    = (const float*)d_in[9];
  const float* simw   = (const float*)d_in[10];
  const float* simb   = (const float*)d_in[11];
  const float* fcw    = (const float*)d_in[12];
  const float* fcb    = (const float*)d_in[13];
  float* ws  = (float*)d_ws;
  float* out = (float*)d_out;

  kz<<<(ZERO_CNT + 255) / 256, 256, 0, stream>>>(ws + OFF_TG, ZERO_CNT);
  k1_stats<<<NROW / (4*RW), 256, 0, stream>>>(text, image, ln_t_w, ln_t_b, ln_i_w, ln_i_b, ws);
  k2_gates<<<HH*HDD/4, 256, 0, stream>>>(Wa, Wab, Wq, Wqb, simw, simb, fcw, ws);
  k3_blend<<<NROW, 256, 0, stream>>>(text, image, ln_t_w, ln_t_b, ln_i_w, ln_i_b, fcb, ws, out);
}

// Round 3
// 272.221 us; speedup vs baseline: 1.8765x; 1.0737x over previous
//
#include <hip/hip_runtime.h>
#include <math.h>

// Problem constants (B,S,D,H) = (8, 2048, 1024, 4), HD = 256
#define BB 8
#define SS 2048
#define DD 1024
#define HH 4
#define HDD 256
#define NROW (BB*SS)           // 16384
#define G 8                    // rows per block in k1
#define NSLICE (NROW/G)        // 2048 partial slices

// Workspace layout (float offsets). Total ~17.1 MB.
#define OFF_MU_T 0
#define OFF_RS_T NROW
#define OFF_MU_I (2*NROW)
#define OFF_RS_I (3*NROW)
#define OFF_PT   (4*NROW)                  // [NSLICE][DD] text-global partials
#define OFF_PI   (OFF_PT + NSLICE*DD)      // [NSLICE][DD] image-global partials
#define OFF_PS   (OFF_PI + NSLICE*DD)      // [NSLICE] sim partials
#define OFF_TG   (OFF_PS + NSLICE)         // [B*D] reduced text-global sum
#define OFF_IG   (OFF_TG + BB*DD)          // [B*D] reduced image-global sum
#define OFF_SIM  (OFF_IG + BB*DD)          // [B] reduced sim sum
#define OFF_LOGIT (OFF_SIM + BB)           // [B]

__device__ __forceinline__ float wred(float v) {
#pragma unroll
  for (int m = 32; m > 0; m >>= 1) v += __shfl_xor(v, m, 64);
  return v;
}

// Pass 1: block per G=8 rows; whole block cooperates on each row.
// Thread owns 4 fixed columns -> LN params live in 16 VGPRs, data in 8+8
// (current + prefetch). Two LDS reduction rounds per row. No global atomics:
// global-mean partials go to a private per-block slice.
__global__ __launch_bounds__(256) void k1_stats(
    const float* __restrict__ text, const float* __restrict__ image,
    const float* __restrict__ wt, const float* __restrict__ bt,
    const float* __restrict__ wi, const float* __restrict__ bi,
    float* __restrict__ ws)
{
  const int g    = blockIdx.x;          // slice id, 0..2047
  const int tid  = threadIdx.x;
  const int lane = tid & 63;
  const int wv   = tid >> 6;
  const int d0   = tid << 2;
  const int row0 = g * G;

  __shared__ float red1[4][4];
  __shared__ float red2[4][4];

  const float4 wt4 = *(const float4*)(wt + d0);
  const float4 bt4 = *(const float4*)(bt + d0);
  const float4 wi4 = *(const float4*)(wi + d0);
  const float4 bi4 = *(const float4*)(bi + d0);

  float4 tga = make_float4(0.f,0.f,0.f,0.f);
  float4 iga = make_float4(0.f,0.f,0.f,0.f);
  float sim_loc = 0.f;

  float4 ct = *(const float4*)(text  + (size_t)row0*DD + d0);
  float4 ci = *(const float4*)(image + (size_t)row0*DD + d0);

  for (int r = 0; r < G; ++r) {
    float4 nt_ = ct, ni_ = ci;
    if (r + 1 < G) {
      nt_ = *(const float4*)(text  + (size_t)(row0+r+1)*DD + d0);
      ni_ = *(const float4*)(image + (size_t)(row0+r+1)*DD + d0);
    }
    // ---- round 1: raw moments ----
    float s1 = ct.x + ct.y + ct.z + ct.w;
    float s2 = ct.x*ct.x + ct.y*ct.y + ct.z*ct.z + ct.w*ct.w;
    float s3 = ci.x + ci.y + ci.z + ci.w;
    float s4 = ci.x*ci.x + ci.y*ci.y + ci.z*ci.z + ci.w*ci.w;
    s1 = wred(s1); s2 = wred(s2); s3 = wred(s3); s4 = wred(s4);
    if (lane == 0) { red1[wv][0]=s1; red1[wv][1]=s2; red1[wv][2]=s3; red1[wv][3]=s4; }
    __syncthreads();
    const float st  = red1[0][0]+red1[1][0]+red1[2][0]+red1[3][0];
    const float sst = red1[0][1]+red1[1][1]+red1[2][1]+red1[3][1];
    const float si  = red1[0][2]+red1[1][2]+red1[2][2]+red1[3][2];
    const float ssi = red1[0][3]+red1[1][3]+red1[2][3]+red1[3][3];
    const float invD = 1.f/DD;
    const float mt = st*invD,  vt = sst*invD - mt*mt;
    const float mi = si*invD,  vi = ssi*invD - mi*mi;
    const float rt = rsqrtf(vt + 1e-5f);
    const float ri = rsqrtf(vi + 1e-5f);
    if (tid == 0) {
      const int row = row0 + r;
      ws[OFF_MU_T+row]=mt; ws[OFF_RS_T+row]=rt;
      ws[OFF_MU_I+row]=mi; ws[OFF_RS_I+row]=ri;
    }
    // ---- round 2: normalized dot / norms / global-mean accumulation ----
    float4 tn, in_;
    tn.x  = (ct.x-mt)*rt*wt4.x + bt4.x;  tn.y  = (ct.y-mt)*rt*wt4.y + bt4.y;
    tn.z  = (ct.z-mt)*rt*wt4.z + bt4.z;  tn.w  = (ct.w-mt)*rt*wt4.w + bt4.w;
    in_.x = (ci.x-mi)*ri*wi4.x + bi4.x;  in_.y = (ci.y-mi)*ri*wi4.y + bi4.y;
    in_.z = (ci.z-mi)*ri*wi4.z + bi4.z;  in_.w = (ci.w-mi)*ri*wi4.w + bi4.w;
    tga.x += tn.x; tga.y += tn.y; tga.z += tn.z; tga.w += tn.w;
    iga.x += in_.x; iga.y += in_.y; iga.z += in_.z; iga.w += in_.w;
    float dv  = tn.x*in_.x + tn.y*in_.y + tn.z*in_.z + tn.w*in_.w;
    float nt2 = tn.x*tn.x + tn.y*tn.y + tn.z*tn.z + tn.w*tn.w;
    float ni2 = in_.x*in_.x + in_.y*in_.y + in_.z*in_.z + in_.w*in_.w;
    dv = wred(dv); nt2 = wred(nt2); ni2 = wred(ni2);
    if (lane == 0) { red2[wv][0]=dv; red2[wv][1]=nt2; red2[wv][2]=ni2; }
    __syncthreads();
    if (tid == 0) {
      const float d_all = red2[0][0]+red2[1][0]+red2[2][0]+red2[3][0];
      const float nt = fmaxf(sqrtf(red2[0][1]+red2[1][1]+red2[2][1]+red2[3][1]), 1e-6f);
      const float ni = fmaxf(sqrtf(red2[0][2]+red2[1][2]+red2[2][2]+red2[3][2]), 1e-6f);
      sim_loc += d_all / (nt*ni);
    }
    ct = nt_; ci = ni_;
  }
  *(float4*)(ws + OFF_PT + (size_t)g*DD + d0) = tga;
  *(float4*)(ws + OFF_PI + (size_t)g*DD + d0) = iga;
  if (tid == 0) ws[OFF_PS + g] = sim_loc;
}

// Reduce partials: blocks 0..31 reduce tg/ig columns; block 32 reduces sim
// and zeroes the logit accumulator.
__global__ __launch_bounds__(256) void kR_reduce(float* __restrict__ ws)
{
  const int tid = threadIdx.x;
  if (blockIdx.x < 32) {
    const int b  = blockIdx.x >> 2;
    const int ch = blockIdx.x & 3;
    const int d  = ch*256 + tid;
    const float* pt = ws + OFF_PT + (size_t)(b*256)*DD + d;
    const float* pi = ws + OFF_PI + (size_t)(b*256)*DD + d;
    float at = 0.f, ai = 0.f;
#pragma unroll 4
    for (int s = 0; s < 256; ++s) {
      at += pt[(size_t)s*DD];
      ai += pi[(size_t)s*DD];
    }
    ws[OFF_TG + b*DD + d] = at;
    ws[OFF_IG + b*DD + d] = ai;
  } else {
    __shared__ float sred[256];
    const int b = tid >> 5, j = tid & 31;
    float a = 0.f;
#pragma unroll
    for (int k = 0; k < 8; ++k) a += ws[OFF_PS + b*256 + j*8 + k];
    sred[tid] = a;
    __syncthreads();
    if (j == 0) {
      float s = 0.f;
#pragma unroll
      for (int m = 0; m < 32; ++m) s += sred[b*32 + m];
      ws[OFF_SIM + b] = s;
    }
    if (tid < BB) ws[OFF_LOGIT + tid] = 0.f;
  }
}

// Gate network: 256 blocks, each owns 4 (h,k) rows; every thread dots its
// float4 of the weight row against all 8 batch global-vectors (L2-hot).
__global__ __launch_bounds__(256) void k2_gates(
    const float* __restrict__ Wa, const float* __restrict__ Wab,
    const float* __restrict__ Wq, const float* __restrict__ Wqb,
    const float* __restrict__ simw, const float* __restrict__ simb,
    const float* __restrict__ fcw, float* __restrict__ ws)
{
  const int tid  = threadIdx.x;
  const int lane = tid & 63;
  const int wv   = tid >> 6;
  const int r0   = blockIdx.x * 4;       // flat (h,k) row base, 0..1023
  const int d0   = tid << 2;

  __shared__ float red[4][4][BB];        // [row][wave][b]

  for (int rr = 0; rr < 4; ++rr) {
    const int r = r0 + rr;
    const float4 a4 = *(const float4*)(Wa + (size_t)r*DD + d0);
    const float4 q4 = *(const float4*)(Wq + (size_t)r*DD + d0);
    float acc[BB];
#pragma unroll
    for (int b = 0; b < BB; ++b) {
      const float4 t = *(const float4*)(ws + OFF_TG + b*DD + d0);
      const float4 i = *(const float4*)(ws + OFF_IG + b*DD + d0);
      acc[b] = a4.x*t.x + a4.y*t.y + a4.z*t.z + a4.w*t.w
             + q4.x*i.x + q4.y*i.y + q4.z*i.z + q4.w*i.w;
    }
#pragma unroll
    for (int b = 0; b < BB; ++b) {
      acc[b] = wred(acc[b]);
      if (lane == 0) red[rr][wv][b] = acc[b];
    }
  }
  __syncthreads();
  if (tid < BB) {
    const int b = tid;
    const float inv = 1.f/SS;
    const float gs = ws[OFF_SIM + b] * inv;   // global_sim[b]
    float part = 0.f;
#pragma unroll
    for (int rr = 0; rr < 4; ++rr) {
      const int r = r0 + rr;
      const int k = r & 255;
      const float v = (red[rr][0][b] + red[rr][1][b] + red[rr][2][b] + red[rr][3][b]) * inv;
      float gate = v + Wab[r] + Wqb[r] + gs*simw[k] + simb[k];
      gate = fmaxf(gate, 0.f);
      part += gate * fcw[r];
    }
    atomicAdd(&ws[OFF_LOGIT + b], part);
  }
}

// Pass 2: 2 rows per block for ILP; tensor loads issued first; recompute
// normalization from stored (mu, rstd), blend with g, write out.
__global__ __launch_bounds__(256) void k3_blend(
    const float* __restrict__ text, const float* __restrict__ image,
    const float* __restrict__ wt, const float* __restrict__ bt,
    const float* __restrict__ wi, const float* __restrict__ bi,
    const float* __restrict__ fcb,
    const float* __restrict__ ws, float* __restrict__ out)
{
  const int r0 = blockIdx.x * 2;
  const int b  = r0 >> 11;      // same b for both rows (r0 even)
  const int d0 = threadIdx.x << 2;

  const float4 ta = *(const float4*)(text  + (size_t)r0*DD + d0);
  const float4 ia = *(const float4*)(image + (size_t)r0*DD + d0);
  const float4 tb = *(const float4*)(text  + (size_t)(r0+1)*DD + d0);
  const float4 ib = *(const float4*)(image + (size_t)(r0+1)*DD + d0);
  const float4 wt4 = *(const float4*)(wt + d0);
  const float4 bt4 = *(const float4*)(bt + d0);
  const float4 wi4 = *(const float4*)(wi + d0);
  const float4 bi4 = *(const float4*)(bi + d0);

  const float g  = 1.f / (1.f + expf(-(ws[OFF_LOGIT+b] + fcb[0])));
  const float gi = 1.f - g;

  const float mta = ws[OFF_MU_T+r0],   rta = ws[OFF_RS_T+r0];
  const float mia = ws[OFF_MU_I+r0],   ria = ws[OFF_RS_I+r0];
  const float mtb = ws[OFF_MU_T+r0+1], rtb = ws[OFF_RS_T+r0+1];
  const float mib = ws[OFF_MU_I+r0+1], rib = ws[OFF_RS_I+r0+1];

  const float gta = g*rta, gia = gi*ria;
  const float gtb = g*rtb, gib = gi*rib;

  float4 oa, ob;
  oa.x = gta*(ta.x-mta)*wt4.x + g*bt4.x + gia*(ia.x-mia)*wi4.x + gi*bi4.x;
  oa.y = gta*(ta.y-mta)*wt4.y + g*bt4.y + gia*(ia.y-mia)*wi4.y + gi*bi4.y;
  oa.z = gta*(ta.z-mta)*wt4.z + g*bt4.z + gia*(ia.z-mia)*wi4.z + gi*bi4.z;
  oa.w = gta*(ta.w-mta)*wt4.w + g*bt4.w + gia*(ia.w-mia)*wi4.w + gi*bi4.w;
  ob.x = gtb*(tb.x-mtb)*wt4.x + g*bt4.x + gib*(ib.x-mib)*wi4.x + gi*bi4.x;
  ob.y = gtb*(tb.y-mtb)*wt4.y + g*bt4.y + gib*(ib.y-mib)*wi4.y + gi*bi4.y;
  ob.z = gtb*(tb.z-mtb)*wt4.z + g*bt4.z + gib*(ib.z-mib)*wi4.z + gi*bi4.z;
  ob.w = gtb*(tb.w-mtb)*wt4.w + g*bt4.w + gib*(ib.w-mib)*wi4.w + gi*bi4.w;

  *(float4*)(out + (size_t)r0*DD + d0)     = oa;
  *(float4*)(out + (size_t)(r0+1)*DD + d0) = ob;
}

extern "C" void kernel_launch(void* const* d_in, const int* in_sizes, int n_in,
                              void* d_out, int out_size, void* d_ws, size_t ws_size,
                              hipStream_t stream)
{
  const float* text   = (const float*)d_in[0];
  const float* image  = (const float*)d_in[1];
  const float* ln_t_w = (const float*)d_in[2];
  const float* ln_t_b = (const float*)d_in[3];
  const float* ln_i_w = (const float*)d_in[4];
  const float* ln_i_b = (const float*)d_in[5];
  const float* Wa     = (const float*)d_in[6];
  const float* Wab    = (const float*)d_in[7];
  const float* Wq     = (const float*)d_in[8];
  const float* Wqb    = (const float*)d_in[9];
  const float* simw   = (const float*)d_in[10];
  const float* simb   = (const float*)d_in[11];
  const float* fcw    = (const float*)d_in[12];
  const float* fcb    = (const float*)d_in[13];
  float* ws  = (float*)d_ws;
  float* out = (float*)d_out;

  k1_stats<<<NSLICE, 256, 0, stream>>>(text, image, ln_t_w, ln_t_b, ln_i_w, ln_i_b, ws);
  kR_reduce<<<33, 256, 0, stream>>>(ws);
  k2_gates<<<HH*HDD/4, 256, 0, stream>>>(Wa, Wab, Wq, Wqb, simw, simb, fcw, ws);
  k3_blend<<<NROW/2, 256, 0, stream>>>(text, image, ln_t_w, ln_t_b, ln_i_w, ln_i_b, fcb, ws, out);
}

// Round 4
// 245.133 us; speedup vs baseline: 2.0838x; 1.1105x over previous
//
#include <hip/hip_runtime.h>
#include <math.h>

// Problem constants (B,S,D,H) = (8, 2048, 1024, 4), HD = 256
#define BB 8
#define SS 2048
#define DD 1024
#define HH 4
#define HDD 256
#define NROW (BB*SS)           // 16384
#define G 8                    // rows per block in k1
#define NSLICE (NROW/G)        // 2048 partial slices

// Workspace layout (float offsets). Total ~17.1 MB.
#define OFF_MU_T 0
#define OFF_RS_T NROW
#define OFF_MU_I (2*NROW)
#define OFF_RS_I (3*NROW)
#define OFF_PT   (4*NROW)                  // [NSLICE][DD] text-global partials
#define OFF_PI   (OFF_PT + NSLICE*DD)      // [NSLICE][DD] image-global partials
#define OFF_PS   (OFF_PI + NSLICE*DD)      // [NSLICE] sim partials
#define OFF_TG   (OFF_PS + NSLICE)         // [B*D] reduced text-global sum
#define OFF_IG   (OFF_TG + BB*DD)          // [B*D] reduced image-global sum
#define OFF_SIM  (OFF_IG + BB*DD)          // [B] reduced sim sum
#define OFF_LOGIT (OFF_SIM + BB)           // [B]

__device__ __forceinline__ float wred(float v) {
#pragma unroll
  for (int m = 32; m > 0; m >>= 1) v += __shfl_xor(v, m, 64);
  return v;
}

__device__ __forceinline__ float hsum(const float4 v) { return v.x+v.y+v.z+v.w; }
__device__ __forceinline__ float hsq(const float4 v)  { return v.x*v.x+v.y*v.y+v.z*v.z+v.w*v.w; }
__device__ __forceinline__ float hdot(const float4 a, const float4 b) {
  return a.x*b.x + a.y*b.y + a.z*b.z + a.w*b.w;
}

// Pass 1: block per G=8 rows, processed 2 rows per reduction round.
// 8 barriers/block (vs 16), 8 independent shuffle chains per round for ILP.
__global__ __launch_bounds__(256) void k1_stats(
    const float* __restrict__ text, const float* __restrict__ image,
    const float* __restrict__ wt, const float* __restrict__ bt,
    const float* __restrict__ wi, const float* __restrict__ bi,
    float* __restrict__ ws)
{
  const int g    = blockIdx.x;          // slice id, 0..2047
  const int tid  = threadIdx.x;
  const int lane = tid & 63;
  const int wv   = tid >> 6;
  const int d0   = tid << 2;
  const int row0 = g * G;

  __shared__ float red1[4][8];
  __shared__ float red2[4][6];

  const float4 wt4 = *(const float4*)(wt + d0);
  const float4 bt4 = *(const float4*)(bt + d0);
  const float4 wi4 = *(const float4*)(wi + d0);
  const float4 bi4 = *(const float4*)(bi + d0);

  float4 tga = make_float4(0.f,0.f,0.f,0.f);
  float4 iga = make_float4(0.f,0.f,0.f,0.f);
  float sim_loc = 0.f;

  for (int r = 0; r < G; r += 2) {
    const size_t base0 = (size_t)(row0 + r) * DD + d0;
    const size_t base1 = base0 + DD;
    const float4 t0 = *(const float4*)(text  + base0);
    const float4 i0 = *(const float4*)(image + base0);
    const float4 t1 = *(const float4*)(text  + base1);
    const float4 i1 = *(const float4*)(image + base1);

    // ---- round 1: raw moments, both rows ----
    float a0 = hsum(t0), a1 = hsq(t0), a2 = hsum(i0), a3 = hsq(i0);
    float a4 = hsum(t1), a5 = hsq(t1), a6 = hsum(i1), a7 = hsq(i1);
    a0 = wred(a0); a1 = wred(a1); a2 = wred(a2); a3 = wred(a3);
    a4 = wred(a4); a5 = wred(a5); a6 = wred(a6); a7 = wred(a7);
    if (lane == 0) {
      red1[wv][0]=a0; red1[wv][1]=a1; red1[wv][2]=a2; red1[wv][3]=a3;
      red1[wv][4]=a4; red1[wv][5]=a5; red1[wv][6]=a6; red1[wv][7]=a7;
    }
    __syncthreads();
    float s[8];
#pragma unroll
    for (int q = 0; q < 8; ++q) s[q] = red1[0][q]+red1[1][q]+red1[2][q]+red1[3][q];
    const float invD = 1.f/DD;
    const float mt0 = s[0]*invD, rt0 = rsqrtf(s[1]*invD - mt0*mt0 + 1e-5f);
    const float mi0 = s[2]*invD, ri0 = rsqrtf(s[3]*invD - mi0*mi0 + 1e-5f);
    const float mt1 = s[4]*invD, rt1 = rsqrtf(s[5]*invD - mt1*mt1 + 1e-5f);
    const float mi1 = s[6]*invD, ri1 = rsqrtf(s[7]*invD - mi1*mi1 + 1e-5f);
    if (tid == 0) {
      const int row = row0 + r;
      ws[OFF_MU_T+row]=mt0;   ws[OFF_RS_T+row]=rt0;
      ws[OFF_MU_I+row]=mi0;   ws[OFF_RS_I+row]=ri0;
      ws[OFF_MU_T+row+1]=mt1; ws[OFF_RS_T+row+1]=rt1;
      ws[OFF_MU_I+row+1]=mi1; ws[OFF_RS_I+row+1]=ri1;
    }
    // ---- round 2: normalized dot/norms, both rows ----
    float4 tn0, in0, tn1, in1;
    tn0.x = (t0.x-mt0)*rt0*wt4.x + bt4.x;  tn0.y = (t0.y-mt0)*rt0*wt4.y + bt4.y;
    tn0.z = (t0.z-mt0)*rt0*wt4.z + bt4.z;  tn0.w = (t0.w-mt0)*rt0*wt4.w + bt4.w;
    in0.x = (i0.x-mi0)*ri0*wi4.x + bi4.x;  in0.y = (i0.y-mi0)*ri0*wi4.y + bi4.y;
    in0.z = (i0.z-mi0)*ri0*wi4.z + bi4.z;  in0.w = (i0.w-mi0)*ri0*wi4.w + bi4.w;
    tn1.x = (t1.x-mt1)*rt1*wt4.x + bt4.x;  tn1.y = (t1.y-mt1)*rt1*wt4.y + bt4.y;
    tn1.z = (t1.z-mt1)*rt1*wt4.z + bt4.z;  tn1.w = (t1.w-mt1)*rt1*wt4.w + bt4.w;
    in1.x = (i1.x-mi1)*ri1*wi4.x + bi4.x;  in1.y = (i1.y-mi1)*ri1*wi4.y + bi4.y;
    in1.z = (i1.z-mi1)*ri1*wi4.z + bi4.z;  in1.w = (i1.w-mi1)*ri1*wi4.w + bi4.w;

    tga.x += tn0.x + tn1.x; tga.y += tn0.y + tn1.y;
    tga.z += tn0.z + tn1.z; tga.w += tn0.w + tn1.w;
    iga.x += in0.x + in1.x; iga.y += in0.y + in1.y;
    iga.z += in0.z + in1.z; iga.w += in0.w + in1.w;

    float b0 = hdot(tn0,in0), b1 = hsq(tn0), b2 = hsq(in0);
    float b3 = hdot(tn1,in1), b4 = hsq(tn1), b5 = hsq(in1);
    b0 = wred(b0); b1 = wred(b1); b2 = wred(b2);
    b3 = wred(b3); b4 = wred(b4); b5 = wred(b5);
    if (lane == 0) {
      red2[wv][0]=b0; red2[wv][1]=b1; red2[wv][2]=b2;
      red2[wv][3]=b3; red2[wv][4]=b4; red2[wv][5]=b5;
    }
    __syncthreads();
    if (tid == 0) {
      float u[6];
#pragma unroll
      for (int q = 0; q < 6; ++q) u[q] = red2[0][q]+red2[1][q]+red2[2][q]+red2[3][q];
      sim_loc += u[0] / (fmaxf(sqrtf(u[1]),1e-6f) * fmaxf(sqrtf(u[2]),1e-6f));
      sim_loc += u[3] / (fmaxf(sqrtf(u[4]),1e-6f) * fmaxf(sqrtf(u[5]),1e-6f));
    }
  }
  *(float4*)(ws + OFF_PT + (size_t)g*DD + d0) = tga;
  *(float4*)(ws + OFF_PI + (size_t)g*DD + d0) = iga;
  if (tid == 0) ws[OFF_PS + g] = sim_loc;
}

// Reduce partials. Blocks 0..255: (b, 32-col chunk) sum 256 slices each,
// coalesced, LDS tree over 8 slice-groups. Block 256: sim + logit zero.
__global__ __launch_bounds__(256) void kR_reduce(float* __restrict__ ws)
{
  const int tid = threadIdx.x;
  if (blockIdx.x < 256) {
    const int b   = blockIdx.x >> 5;       // 0..7
    const int ch  = blockIdx.x & 31;       // 32-col chunk
    const int cl  = tid & 31;
    const int sg  = tid >> 5;              // 0..7 slice-group
    const int col = ch*32 + cl;
    const float* pt = ws + OFF_PT + (size_t)(b*256 + sg*32)*DD + col;
    const float* pi = ws + OFF_PI + (size_t)(b*256 + sg*32)*DD + col;
    float at = 0.f, ai = 0.f;
#pragma unroll 4
    for (int k = 0; k < 32; ++k) {
      at += pt[(size_t)k*DD];
      ai += pi[(size_t)k*DD];
    }
    __shared__ float sred[2][8][32];
    sred[0][sg][cl] = at;
    sred[1][sg][cl] = ai;
    __syncthreads();
    if (tid < 32) {
      float v = 0.f;
#pragma unroll
      for (int q = 0; q < 8; ++q) v += sred[0][q][tid];
      ws[OFF_TG + b*DD + ch*32 + tid] = v;
    } else if (tid < 64) {
      const int c = tid - 32;
      float v = 0.f;
#pragma unroll
      for (int q = 0; q < 8; ++q) v += sred[1][q][c];
      ws[OFF_IG + b*DD + ch*32 + c] = v;
    }
  } else {
    __shared__ float sred[256];
    const int b = tid >> 5, j = tid & 31;
    float a = 0.f;
#pragma unroll
    for (int k = 0; k < 8; ++k) a += ws[OFF_PS + b*256 + j*8 + k];
    sred[tid] = a;
    __syncthreads();
    if (j == 0) {
      float s = 0.f;
#pragma unroll
      for (int m = 0; m < 32; ++m) s += sred[b*32 + m];
      ws[OFF_SIM + b] = s;
    }
    if (tid < BB) ws[OFF_LOGIT + tid] = 0.f;
  }
}

// Gate network: 256 blocks, each owns 4 (h,k) rows; every thread dots its
// float4 of the weight row against all 8 batch global-vectors (L2-hot).
__global__ __launch_bounds__(256) void k2_gates(
    const float* __restrict__ Wa, const float* __restrict__ Wab,
    const float* __restrict__ Wq, const float* __restrict__ Wqb,
    const float* __restrict__ simw, const float* __restrict__ simb,
    const float* __restrict__ fcw, float* __restrict__ ws)
{
  const int tid  = threadIdx.x;
  const int lane = tid & 63;
  const int wv   = tid >> 6;
  const int r0   = blockIdx.x * 4;       // flat (h,k) row base, 0..1023
  const int d0   = tid << 2;

  __shared__ float red[4][4][BB];        // [row][wave][b]

  for (int rr = 0; rr < 4; ++rr) {
    const int r = r0 + rr;
    const float4 a4 = *(const float4*)(Wa + (size_t)r*DD + d0);
    const float4 q4 = *(const float4*)(Wq + (size_t)r*DD + d0);
    float acc[BB];
#pragma unroll
    for (int b = 0; b < BB; ++b) {
      const float4 t = *(const float4*)(ws + OFF_TG + b*DD + d0);
      const float4 i = *(const float4*)(ws + OFF_IG + b*DD + d0);
      acc[b] = hdot(a4, t) + hdot(q4, i);
    }
#pragma unroll
    for (int b = 0; b < BB; ++b) {
      acc[b] = wred(acc[b]);
      if (lane == 0) red[rr][wv][b] = acc[b];
    }
  }
  __syncthreads();
  if (tid < BB) {
    const int b = tid;
    const float inv = 1.f/SS;
    const float gs = ws[OFF_SIM + b] * inv;   // global_sim[b]
    float part = 0.f;
#pragma unroll
    for (int rr = 0; rr < 4; ++rr) {
      const int r = r0 + rr;
      const int k = r & 255;
      const float v = (red[rr][0][b] + red[rr][1][b] + red[rr][2][b] + red[rr][3][b]) * inv;
      float gate = v + Wab[r] + Wqb[r] + gs*simw[k] + simb[k];
      gate = fmaxf(gate, 0.f);
      part += gate * fcw[r];
    }
    atomicAdd(&ws[OFF_LOGIT + b], part);
  }
}

// Pass 2: 4 rows per block; all 8 tensor loads issued before any compute.
__global__ __launch_bounds__(256) void k3_blend(
    const float* __restrict__ text, const float* __restrict__ image,
    const float* __restrict__ wt, const float* __restrict__ bt,
    const float* __restrict__ wi, const float* __restrict__ bi,
    const float* __restrict__ fcb,
    const float* __restrict__ ws, float* __restrict__ out)
{
  const int r0 = blockIdx.x * 4;
  const int b  = r0 >> 11;      // same b for all 4 rows (r0 % 4 == 0)
  const int d0 = threadIdx.x << 2;

  float4 t[4], im[4];
#pragma unroll
  for (int r = 0; r < 4; ++r) {
    t[r]  = *(const float4*)(text  + (size_t)(r0+r)*DD + d0);
    im[r] = *(const float4*)(image + (size_t)(r0+r)*DD + d0);
  }
  const float4 wt4 = *(const float4*)(wt + d0);
  const float4 bt4 = *(const float4*)(bt + d0);
  const float4 wi4 = *(const float4*)(wi + d0);
  const float4 bi4 = *(const float4*)(bi + d0);

  const float g  = 1.f / (1.f + expf(-(ws[OFF_LOGIT+b] + fcb[0])));
  const float gi = 1.f - g;

#pragma unroll
  for (int r = 0; r < 4; ++r) {
    const float mt = ws[OFF_MU_T+r0+r], rt = ws[OFF_RS_T+r0+r];
    const float mi = ws[OFF_MU_I+r0+r], ri = ws[OFF_RS_I+r0+r];
    const float gt = g*rt, gii = gi*ri;
    float4 o;
    o.x = gt*(t[r].x-mt)*wt4.x + g*bt4.x + gii*(im[r].x-mi)*wi4.x + gi*bi4.x;
    o.y = gt*(t[r].y-mt)*wt4.y + g*bt4.y + gii*(im[r].y-mi)*wi4.y + gi*bi4.y;
    o.z = gt*(t[r].z-mt)*wt4.z + g*bt4.z + gii*(im[r].z-mi)*wi4.z + gi*bi4.z;
    o.w = gt*(t[r].w-mt)*wt4.w + g*bt4.w + gii*(im[r].w-mi)*wi4.w + gi*bi4.w;
    *(float4*)(out + (size_t)(r0+r)*DD + d0) = o;
  }
}

extern "C" void kernel_launch(void* const* d_in, const int* in_sizes, int n_in,
                              void* d_out, int out_size, void* d_ws, size_t ws_size,
                              hipStream_t stream)
{
  const float* text   = (const float*)d_in[0];
  const float* image  = (const float*)d_in[1];
  const float* ln_t_w = (const float*)d_in[2];
  const float* ln_t_b = (const float*)d_in[3];
  const float* ln_i_w = (const float*)d_in[4];
  const float* ln_i_b = (const float*)d_in[5];
  const float* Wa     = (const float*)d_in[6];
  const float* Wab    = (const float*)d_in[7];
  const float* Wq     = (const float*)d_in[8];
  const float* Wqb    = (const float*)d_in[9];
  const float* simw   = (const float*)d_in[10];
  const float* simb   = (const float*)d_in[11];
  const float* fcw    = (const float*)d_in[12];
  const float* fcb    = (const float*)d_in[13];
  float* ws  = (float*)d_ws;
  float* out = (float*)d_out;

  k1_stats<<<NSLICE, 256, 0, stream>>>(text, image, ln_t_w, ln_t_b, ln_i_w, ln_i_b, ws);
  kR_reduce<<<257, 256, 0, stream>>>(ws);
  k2_gates<<<HH*HDD/4, 256, 0, stream>>>(Wa, Wab, Wq, Wqb, simw, simb, fcw, ws);
  k3_blend<<<NROW/4, 256, 0, stream>>>(text, image, ln_t_w, ln_t_b, ln_i_w, ln_i_b, fcb, ws, out);
}